// Round 11
// baseline (79.250 us; speedup 1.0000x reference)
//
#include <hip/hip_runtime.h>
#include <float.h>
#include <math.h>

#define B 128
#define D 128
#define N 3072      // 3*32*32
#define NBUCK 2048  // value buckets (uniform [0,1) -> ~1.5 elems/bucket)
#define TROW 64     // row-tiles (2 rows each)
#define NTILE (TROW*(TROW+1)/2)   // 2080 upper-tri 2x2 tiles
#define NTHREADS 512
#define PAIR_BLOCKS 1040          // 2 tiles/block * 1040 = 2080 exact

__device__ __forceinline__ void cas_asc(float& a, float& b) {
    float lo = fminf(a, b), hi = fmaxf(a, b);
    a = lo; b = hi;
}

// ---------------------------------------------------------------------------
// K1: blocks 0..127 bucket-sort x row bid -> xs (validated R9/R10 pipeline:
//     2048 buckets, non-unrolled per-bucket loop, bitonic-8/16 in registers,
//     LDS insertion fallback). Blocks 128..255: zcos row (bid-128)
//     (validated shape); block 128 additionally zeroes out AND computes
//     maxv once via the R5-validated diag-recompute (bitwise-identical to
//     the zcos diagonal) -> ws, so pair blocks need no diagonal gather.
// ---------------------------------------------------------------------------
__global__ __launch_bounds__(NTHREADS) void prep_kernel(const float* __restrict__ x,
                                                        const float* __restrict__ z,
                                                        float* __restrict__ xs,
                                                        float* __restrict__ zcos,
                                                        float* __restrict__ maxv_ws,
                                                        float* __restrict__ out) {
    __shared__ unsigned hist[NBUCK];
    __shared__ unsigned bbase[NBUCK];
    __shared__ unsigned wsum[8];
    __shared__ unsigned wpre[8];
    __shared__ float scat[N];      // scattered (bucket-grouped) elements
    __shared__ float inv_s[B];
    __shared__ float diag[B];

    int tid = threadIdx.x;
    int bid = blockIdx.x;
    int lane = tid & 63;
    int wid = tid >> 6;

    if (bid < B) {
        // ================= bucket sort of row bid (validated) ============
        int row = bid;
        float v[6]; int bb[6];
        const float2* xr = (const float2*)(x + (size_t)row * N);
        #pragma unroll
        for (int k = 0; k < 3; k++) {
            float2 t = xr[tid + k * 512];
            v[2 * k] = t.x; v[2 * k + 1] = t.y;
        }
        #pragma unroll
        for (int k = 0; k < 6; k++) {
            int b = (int)(v[k] * (float)NBUCK);   // monotone in v
            bb[k] = b < 0 ? 0 : (b > NBUCK - 1 ? NBUCK - 1 : b);
        }
        #pragma unroll
        for (int k = 0; k < 4; k++) hist[tid + k * 512] = 0;
        __syncthreads();
        #pragma unroll
        for (int k = 0; k < 6; k++) atomicAdd(&hist[bb[k]], 1u);
        __syncthreads();

        // exclusive scan over 2048 bucket counts (4 buckets/thread, contig)
        unsigned c[4];
        unsigned tsum = 0;
        #pragma unroll
        for (int k = 0; k < 4; k++) { c[k] = hist[4 * tid + k]; tsum += c[k]; }
        unsigned ps = tsum;
        #pragma unroll
        for (int o = 1; o < 64; o <<= 1) {         // wave inclusive scan
            unsigned t = __shfl_up(ps, o, 64);
            if (lane >= o) ps += t;
        }
        if (lane == 63) wsum[wid] = ps;
        __syncthreads();
        if (tid == 0) {
            unsigned acc = 0;
            #pragma unroll
            for (int i = 0; i < 8; i++) { wpre[i] = acc; acc += wsum[i]; }
        }
        __syncthreads();
        unsigned excl = ps - tsum + wpre[wid];
        #pragma unroll
        for (int k = 0; k < 4; k++) { bbase[4 * tid + k] = excl; excl += c[k]; }
        __syncthreads();

        // scatter (rank via atomicAdd; bbase[b] ends at bucket end)
        #pragma unroll
        for (int k = 0; k < 6; k++) {
            unsigned pos = atomicAdd(&bbase[bb[k]], 1u);
            scat[pos] = v[k];
        }
        __syncthreads();

        // per-bucket sort: 4 buckets/thread, ONE at a time (no spill)
        #pragma unroll 1
        for (int t = 0; t < 4; t++) {
            int b = 4 * tid + t;
            int end = (int)bbase[b];
            int m   = (int)hist[b];
            int st  = end - m;
            if (m > 1) {
                if (m <= 8) {
                    float e[8];
                    #pragma unroll
                    for (int i = 0; i < 8; i++)
                        e[i] = (i < m) ? scat[st + i] : FLT_MAX;
                    #pragma unroll
                    for (int k = 2; k <= 8; k <<= 1) {
                        #pragma unroll
                        for (int j = k >> 1; j >= 1; j >>= 1) {
                            #pragma unroll
                            for (int i = 0; i < 8; i++) {
                                int l = i ^ j;
                                if (l > i) {
                                    if ((i & k) == 0) cas_asc(e[i], e[l]);
                                    else              cas_asc(e[l], e[i]);
                                }
                            }
                        }
                    }
                    #pragma unroll
                    for (int i = 0; i < 8; i++)
                        if (i < m) scat[st + i] = e[i];
                } else if (m <= 16) {
                    float e[16];
                    #pragma unroll
                    for (int i = 0; i < 16; i++)
                        e[i] = (i < m) ? scat[st + i] : FLT_MAX;
                    #pragma unroll
                    for (int k = 2; k <= 16; k <<= 1) {
                        #pragma unroll
                        for (int j = k >> 1; j >= 1; j >>= 1) {
                            #pragma unroll
                            for (int i = 0; i < 16; i++) {
                                int l = i ^ j;
                                if (l > i) {
                                    if ((i & k) == 0) cas_asc(e[i], e[l]);
                                    else              cas_asc(e[l], e[i]);
                                }
                            }
                        }
                    }
                    #pragma unroll
                    for (int i = 0; i < 16; i++)
                        if (i < m) scat[st + i] = e[i];
                } else {
                    // fallback (never taken for uniform data): LDS insertion
                    for (int i = st + 1; i < end; i++) {
                        float key = scat[i];
                        int j2 = i - 1;
                        while (j2 >= st && scat[j2] > key) {
                            scat[j2 + 1] = scat[j2];
                            j2--;
                        }
                        scat[j2 + 1] = key;
                    }
                }
            }
        }
        __syncthreads();

        // coalesced plain stores (kernel boundary provides coherence)
        float4* dst = (float4*)(xs + (size_t)row * N);
        dst[tid] = ((const float4*)scat)[tid];
        if (tid < 256) dst[tid + 512] = ((const float4*)scat)[tid + 512];
    } else {
        // ================= zcos row r = bid - 128 (validated) ============
        int r = bid - B;
        if (bid == B && tid == 0) out[0] = 0.f;

        // all-row inverse norms (4 threads per row)
        {
            int r2 = tid >> 2, seg = tid & 3;
            const float4* zr = (const float4*)(z + r2 * D + seg * 32);
            float s = 0.f;
            #pragma unroll
            for (int u = 0; u < 8; u++) {
                float4 vv = zr[u];
                s += vv.x * vv.x + vv.y * vv.y + vv.z * vv.z + vv.w * vv.w;
            }
            s += __shfl_down(s, 2, 4);
            s += __shfl_down(s, 1, 4);
            if (seg == 0) inv_s[r2] = 1.0f / fmaxf(sqrtf(s), 1e-12f);
        }
        __syncthreads();

        // zcos row r: 128 entries, 8 threads/entry, 2 reps (validated shape)
        int e = tid >> 3, sg = tid & 7;
        #pragma unroll
        for (int rep = 0; rep < 2; rep++) {
            int j = e + rep * 64;
            const float4* zi = (const float4*)(z + r * D + sg * 16);
            const float4* zj = (const float4*)(z + j * D + sg * 16);
            float dot = 0.f;
            #pragma unroll
            for (int u = 0; u < 4; u++) {
                float4 a = zi[u], b = zj[u];
                dot += a.x * b.x + a.y * b.y + a.z * b.z + a.w * b.w;
            }
            dot += __shfl_down(dot, 4, 8);
            dot += __shfl_down(dot, 2, 8);
            dot += __shfl_down(dot, 1, 8);
            if (sg == 0) zcos[r * B + j] = dot * inv_s[r] * inv_s[j];
        }

        // block B only: maxv via R5-validated diag recompute (bit-identical
        // to the zcos diagonal arithmetic), stored once to ws.
        if (bid == B) {
            #pragma unroll
            for (int rep = 0; rep < 2; rep++) {
                int er = e + rep * 64;
                const float4* zi = (const float4*)(z + er * D + sg * 16);
                const float4* zj = (const float4*)(z + er * D + sg * 16);
                float dot = 0.f;
                #pragma unroll
                for (int u = 0; u < 4; u++) {
                    float4 a = zi[u], b = zj[u];
                    dot += a.x * b.x + a.y * b.y + a.z * b.z + a.w * b.w;
                }
                dot += __shfl_down(dot, 4, 8);
                dot += __shfl_down(dot, 2, 8);
                dot += __shfl_down(dot, 1, 8);
                if (sg == 0) diag[er] = dot * inv_s[er] * inv_s[er];
            }
            __syncthreads();
            if (tid < 64) {
                float vv = fmaxf(diag[tid], diag[tid + 64]);
                #pragma unroll
                for (int o = 32; o > 0; o >>= 1)
                    vv = fmaxf(vv, __shfl_down(vv, o, 64));
                if (tid == 0) maxv_ws[0] = vv;
            }
        }
    }
}

// ---------------------------------------------------------------------------
// K2: pair tiles, latency-optimized. 1040 blocks x 256 threads (4 waves):
// block handles 2 tiles; each tile computed by 2 column-half waves (6 of the
// 12 iterations each) -> 4160 waves (~4/SIMD, ~4 blocks/CU) vs R10's 2/SIMD.
// Halves combined via LDS; maxv read from ws (hoisted to prep); validated
// decode/weights; bijective XCD swizzle (1040 = 8*130); 1 atomicAdd/block.
// ---------------------------------------------------------------------------
__global__ __launch_bounds__(256, 4) void pair_kernel(const float* __restrict__ xs,
                                                      const float* __restrict__ zcos,
                                                      const float* __restrict__ maxv_ws,
                                                      float* __restrict__ out) {
    __shared__ float4 pt[4];       // per-wave partial (s00,s01,s10,s11)
    __shared__ int sti[2], stj[2];
    __shared__ float partial[2];

    int tid = threadIdx.x;
    int bid = blockIdx.x;
    int lane = tid & 63;
    int w = tid >> 6;              // wave 0..3
    int tw = w >> 1;               // tile within block 0..1
    int half = w & 1;              // column half

    int swz = (bid & 7) * 130 + (bid >> 3);   // bijective on [0,1040)
    int T = 2 * swz + tw;                     // < 2080 exact

    // decode T -> (ti, tj), ti<=tj over TROW=64 (validated decode)
    float ff = (float)(2 * TROW + 1);
    int ti = (int)((ff - sqrtf(ff * ff - 8.0f * (float)T)) * 0.5f);
    if (ti < 0) ti = 0;
    if (ti > TROW - 1) ti = TROW - 1;
    while ((ti + 1) * TROW - ((ti + 1) * ti) / 2 <= T) ti++;
    while (ti * TROW - (ti * (ti - 1)) / 2 > T) ti--;
    int tj = ti + (T - (ti * TROW - (ti * (ti - 1)) / 2));

    if (half == 0 && lane == 0) { sti[tw] = ti; stj[tw] = tj; }

    int r0 = 2 * ti, r1 = r0 + 1;
    int c0 = 2 * tj, c1 = c0 + 1;

    const float4* a0 = (const float4*)(xs + (size_t)r0 * N);
    const float4* a1 = (const float4*)(xs + (size_t)r1 * N);
    const float4* b0 = (const float4*)(xs + (size_t)c0 * N);
    const float4* b1 = (const float4*)(xs + (size_t)c1 * N);

    float s00 = 0.f, s01 = 0.f, s10 = 0.f, s11 = 0.f;
    int base = half * 384;          // 6 of 12 iterations per half
    #pragma unroll
    for (int u = 0; u < 6; u++) {
        int idx = base + u * 64 + lane;
        float4 va0 = a0[idx], va1 = a1[idx];
        float4 vb0 = b0[idx], vb1 = b1[idx];
        s00 += fabsf(va0.x - vb0.x) + fabsf(va0.y - vb0.y)
             + fabsf(va0.z - vb0.z) + fabsf(va0.w - vb0.w);
        s01 += fabsf(va0.x - vb1.x) + fabsf(va0.y - vb1.y)
             + fabsf(va0.z - vb1.z) + fabsf(va0.w - vb1.w);
        s10 += fabsf(va1.x - vb0.x) + fabsf(va1.y - vb0.y)
             + fabsf(va1.z - vb0.z) + fabsf(va1.w - vb0.w);
        s11 += fabsf(va1.x - vb1.x) + fabsf(va1.y - vb1.y)
             + fabsf(va1.z - vb1.z) + fabsf(va1.w - vb1.w);
    }
    #pragma unroll
    for (int o = 32; o > 0; o >>= 1) {
        s00 += __shfl_down(s00, o, 64);
        s01 += __shfl_down(s01, o, 64);
        s10 += __shfl_down(s10, o, 64);
        s11 += __shfl_down(s11, o, 64);
    }
    if (lane == 0) pt[w] = make_float4(s00, s01, s10, s11);
    __syncthreads();

    if (tid < 2) {
        float4 pa = pt[2 * tid], pb = pt[2 * tid + 1];
        float t00 = pa.x + pb.x, t01 = pa.y + pb.y;
        float t10 = pa.z + pb.z, t11 = pa.w + pb.w;
        int i2 = sti[tid], j2 = stj[tid];
        int rr0 = 2 * i2, rr1 = rr0 + 1;
        int cc0 = 2 * j2, cc1 = cc0 + 1;
        float maxv = maxv_ws[0];
        bool diagt = (i2 == j2);
        float w00 = diagt ? 1.0f : 2.0f;
        float w01 = 2.0f;
        float w10 = diagt ? 0.0f : 2.0f;
        float w11 = diagt ? 1.0f : 2.0f;
        float inv_n = 1.0f / N;
        float d00 = t00 * inv_n - (maxv - zcos[rr0 * B + cc0]);
        float d01 = t01 * inv_n - (maxv - zcos[rr0 * B + cc1]);
        float d10 = t10 * inv_n - (maxv - zcos[rr1 * B + cc0]);
        float d11 = t11 * inv_n - (maxv - zcos[rr1 * B + cc1]);
        partial[tid] = w00 * d00 * d00 + w01 * d01 * d01
                     + w10 * d10 * d10 + w11 * d11 * d11;
    }
    __syncthreads();
    if (tid == 0)
        atomicAdd(out, (partial[0] + partial[1]) * (1.0f / (B * B)));
}

extern "C" void kernel_launch(void* const* d_in, const int* in_sizes, int n_in,
                              void* d_out, int out_size, void* d_ws, size_t ws_size,
                              hipStream_t stream) {
    const float* z = (const float*)d_in[0];   // [128,128]
    const float* x = (const float*)d_in[1];   // [128,3,32,32]
    float* out = (float*)d_out;               // [1]
    float* ws = (float*)d_ws;

    float* zcos = ws;                         // 16384 floats
    float* xs   = ws + 16384;                 // 393216 floats (sorted rows)
    float* maxv = ws + 16384 + 393216;        // 1 float

    prep_kernel<<<2 * B, NTHREADS, 0, stream>>>(x, z, xs, zcos, maxv, out);
    pair_kernel<<<PAIR_BLOCKS, 256, 0, stream>>>(xs, zcos, maxv, out);
}

// Round 12
// 70.995 us; speedup vs baseline: 1.1163x; 1.1163x over previous
//
#include <hip/hip_runtime.h>
#include <float.h>
#include <math.h>

#define B 128
#define D 128
#define N 3072      // 3*32*32
#define NBUCK 2048  // value buckets (uniform [0,1) -> ~1.5 elems/bucket)
#define TROW 64     // row-tiles (2 rows each)
#define NTILE (TROW*(TROW+1)/2)   // 2080 upper-tri 2x2 tiles
#define NTHREADS 512

__device__ __forceinline__ void cas_asc(float& a, float& b) {
    float lo = fminf(a, b), hi = fmaxf(a, b);
    a = lo; b = hi;
}

// ---------------------------------------------------------------------------
// K1 (validated R9/R10 pipeline): blocks 0..127 bucket-sort x row bid -> xs
//     (2048 buckets, non-unrolled per-bucket loop, in-register bitonic-8/16,
//     LDS insertion fallback). Blocks 128..255: zcos row (bid-128); block
//     128 zeroes out AND computes maxv once (R5-validated diag recompute,
//     bit-identical to the zcos diagonal) -> ws. Plain stores; kernel
//     boundary provides cross-XCD coherence.
// ---------------------------------------------------------------------------
__global__ __launch_bounds__(NTHREADS) void prep_kernel(const float* __restrict__ x,
                                                        const float* __restrict__ z,
                                                        float* __restrict__ xs,
                                                        float* __restrict__ zcos,
                                                        float* __restrict__ maxv_ws,
                                                        float* __restrict__ out) {
    __shared__ unsigned hist[NBUCK];
    __shared__ unsigned bbase[NBUCK];
    __shared__ unsigned wsum[8];
    __shared__ unsigned wpre[8];
    __shared__ float scat[N];      // scattered (bucket-grouped) elements
    __shared__ float inv_s[B];
    __shared__ float diag[B];

    int tid = threadIdx.x;
    int bid = blockIdx.x;
    int lane = tid & 63;
    int wid = tid >> 6;

    if (bid < B) {
        // ================= bucket sort of row bid (validated) ============
        int row = bid;
        float v[6]; int bb[6];
        const float2* xr = (const float2*)(x + (size_t)row * N);
        #pragma unroll
        for (int k = 0; k < 3; k++) {
            float2 t = xr[tid + k * 512];
            v[2 * k] = t.x; v[2 * k + 1] = t.y;
        }
        #pragma unroll
        for (int k = 0; k < 6; k++) {
            int b = (int)(v[k] * (float)NBUCK);   // monotone in v
            bb[k] = b < 0 ? 0 : (b > NBUCK - 1 ? NBUCK - 1 : b);
        }
        #pragma unroll
        for (int k = 0; k < 4; k++) hist[tid + k * 512] = 0;
        __syncthreads();
        #pragma unroll
        for (int k = 0; k < 6; k++) atomicAdd(&hist[bb[k]], 1u);
        __syncthreads();

        // exclusive scan over 2048 bucket counts (4 buckets/thread, contig)
        unsigned c[4];
        unsigned tsum = 0;
        #pragma unroll
        for (int k = 0; k < 4; k++) { c[k] = hist[4 * tid + k]; tsum += c[k]; }
        unsigned ps = tsum;
        #pragma unroll
        for (int o = 1; o < 64; o <<= 1) {         // wave inclusive scan
            unsigned t = __shfl_up(ps, o, 64);
            if (lane >= o) ps += t;
        }
        if (lane == 63) wsum[wid] = ps;
        __syncthreads();
        if (tid == 0) {
            unsigned acc = 0;
            #pragma unroll
            for (int i = 0; i < 8; i++) { wpre[i] = acc; acc += wsum[i]; }
        }
        __syncthreads();
        unsigned excl = ps - tsum + wpre[wid];
        #pragma unroll
        for (int k = 0; k < 4; k++) { bbase[4 * tid + k] = excl; excl += c[k]; }
        __syncthreads();

        // scatter (rank via atomicAdd; bbase[b] ends at bucket end)
        #pragma unroll
        for (int k = 0; k < 6; k++) {
            unsigned pos = atomicAdd(&bbase[bb[k]], 1u);
            scat[pos] = v[k];
        }
        __syncthreads();

        // per-bucket sort: 4 buckets/thread, ONE at a time (no spill)
        #pragma unroll 1
        for (int t = 0; t < 4; t++) {
            int b = 4 * tid + t;
            int end = (int)bbase[b];
            int m   = (int)hist[b];
            int st  = end - m;
            if (m > 1) {
                if (m <= 8) {
                    float e[8];
                    #pragma unroll
                    for (int i = 0; i < 8; i++)
                        e[i] = (i < m) ? scat[st + i] : FLT_MAX;
                    #pragma unroll
                    for (int k = 2; k <= 8; k <<= 1) {
                        #pragma unroll
                        for (int j = k >> 1; j >= 1; j >>= 1) {
                            #pragma unroll
                            for (int i = 0; i < 8; i++) {
                                int l = i ^ j;
                                if (l > i) {
                                    if ((i & k) == 0) cas_asc(e[i], e[l]);
                                    else              cas_asc(e[l], e[i]);
                                }
                            }
                        }
                    }
                    #pragma unroll
                    for (int i = 0; i < 8; i++)
                        if (i < m) scat[st + i] = e[i];
                } else if (m <= 16) {
                    float e[16];
                    #pragma unroll
                    for (int i = 0; i < 16; i++)
                        e[i] = (i < m) ? scat[st + i] : FLT_MAX;
                    #pragma unroll
                    for (int k = 2; k <= 16; k <<= 1) {
                        #pragma unroll
                        for (int j = k >> 1; j >= 1; j >>= 1) {
                            #pragma unroll
                            for (int i = 0; i < 16; i++) {
                                int l = i ^ j;
                                if (l > i) {
                                    if ((i & k) == 0) cas_asc(e[i], e[l]);
                                    else              cas_asc(e[l], e[i]);
                                }
                            }
                        }
                    }
                    #pragma unroll
                    for (int i = 0; i < 16; i++)
                        if (i < m) scat[st + i] = e[i];
                } else {
                    // fallback (never taken for uniform data): LDS insertion
                    for (int i = st + 1; i < end; i++) {
                        float key = scat[i];
                        int j2 = i - 1;
                        while (j2 >= st && scat[j2] > key) {
                            scat[j2 + 1] = scat[j2];
                            j2--;
                        }
                        scat[j2 + 1] = key;
                    }
                }
            }
        }
        __syncthreads();

        // coalesced plain stores (kernel boundary provides coherence)
        float4* dst = (float4*)(xs + (size_t)row * N);
        dst[tid] = ((const float4*)scat)[tid];
        if (tid < 256) dst[tid + 512] = ((const float4*)scat)[tid + 512];
    } else {
        // ================= zcos row r = bid - 128 (validated) ============
        int r = bid - B;
        if (bid == B && tid == 0) out[0] = 0.f;

        // all-row inverse norms (4 threads per row)
        {
            int r2 = tid >> 2, seg = tid & 3;
            const float4* zr = (const float4*)(z + r2 * D + seg * 32);
            float s = 0.f;
            #pragma unroll
            for (int u = 0; u < 8; u++) {
                float4 vv = zr[u];
                s += vv.x * vv.x + vv.y * vv.y + vv.z * vv.z + vv.w * vv.w;
            }
            s += __shfl_down(s, 2, 4);
            s += __shfl_down(s, 1, 4);
            if (seg == 0) inv_s[r2] = 1.0f / fmaxf(sqrtf(s), 1e-12f);
        }
        __syncthreads();

        // zcos row r: 128 entries, 8 threads/entry, 2 reps (validated shape)
        int e = tid >> 3, sg = tid & 7;
        #pragma unroll
        for (int rep = 0; rep < 2; rep++) {
            int j = e + rep * 64;
            const float4* zi = (const float4*)(z + r * D + sg * 16);
            const float4* zj = (const float4*)(z + j * D + sg * 16);
            float dot = 0.f;
            #pragma unroll
            for (int u = 0; u < 4; u++) {
                float4 a = zi[u], b = zj[u];
                dot += a.x * b.x + a.y * b.y + a.z * b.z + a.w * b.w;
            }
            dot += __shfl_down(dot, 4, 8);
            dot += __shfl_down(dot, 2, 8);
            dot += __shfl_down(dot, 1, 8);
            if (sg == 0) zcos[r * B + j] = dot * inv_s[r] * inv_s[j];
        }

        // block B only: maxv via R5-validated diag recompute (bit-identical
        // to the zcos diagonal arithmetic), stored once to ws.
        if (bid == B) {
            #pragma unroll
            for (int rep = 0; rep < 2; rep++) {
                int er = e + rep * 64;
                const float4* zi = (const float4*)(z + er * D + sg * 16);
                const float4* zj = (const float4*)(z + er * D + sg * 16);
                float dot = 0.f;
                #pragma unroll
                for (int u = 0; u < 4; u++) {
                    float4 a = zi[u], b = zj[u];
                    dot += a.x * b.x + a.y * b.y + a.z * b.z + a.w * b.w;
                }
                dot += __shfl_down(dot, 4, 8);
                dot += __shfl_down(dot, 2, 8);
                dot += __shfl_down(dot, 1, 8);
                if (sg == 0) diag[er] = dot * inv_s[er] * inv_s[er];
            }
            __syncthreads();
            if (tid < 64) {
                float vv = fmaxf(diag[tid], diag[tid + 64]);
                #pragma unroll
                for (int o = 32; o > 0; o >>= 1)
                    vv = fmaxf(vv, __shfl_down(vv, o, 64));
                if (tid == 0) maxv_ws[0] = vv;
            }
        }
    }
}

// ---------------------------------------------------------------------------
// K2: pair tiles — EXACT R10 structure (best measured: 256 blocks x 512
// threads, 8 waves, 1 tile/wave, bijective XCD swizzle, validated decode/
// weights, 1 atomicAdd/block). Single change vs R10: maxv read from ws
// (hoisted to prep) instead of a per-block 128-entry stride-129 gather.
// ---------------------------------------------------------------------------
__global__ __launch_bounds__(NTHREADS) void pair_kernel(const float* __restrict__ xs,
                                                        const float* __restrict__ zcos,
                                                        const float* __restrict__ maxv_ws,
                                                        float* __restrict__ out) {
    __shared__ float partial[8];
    int tid = threadIdx.x;
    int bid = blockIdx.x;
    int lane = tid & 63;
    int w = tid >> 6;
    int swz = ((bid & 7) << 5) | (bid >> 3);   // bijective on [0,256)

    float maxv = maxv_ws[0];                   // hoisted (computed in prep)

    float acc = 0.f;
    int nT = (w == 0 && (swz & 7) == 0) ? 2 : 1;
    for (int pass = 0; pass < nT; ++pass) {
        int T = (pass == 0) ? (swz * 8 + w) : (2048 + (swz >> 3));

        // decode T -> (ti, tj), ti<=tj over TROW=64 (validated decode)
        float ff = (float)(2 * TROW + 1);
        int ti = (int)((ff - sqrtf(ff * ff - 8.0f * (float)T)) * 0.5f);
        if (ti < 0) ti = 0;
        if (ti > TROW - 1) ti = TROW - 1;
        while ((ti + 1) * TROW - ((ti + 1) * ti) / 2 <= T) ti++;
        while (ti * TROW - (ti * (ti - 1)) / 2 > T) ti--;
        int tj = ti + (T - (ti * TROW - (ti * (ti - 1)) / 2));

        int r0 = 2 * ti, r1 = r0 + 1;
        int c0 = 2 * tj, c1 = c0 + 1;

        const float4* a0 = (const float4*)(xs + (size_t)r0 * N);
        const float4* a1 = (const float4*)(xs + (size_t)r1 * N);
        const float4* b0 = (const float4*)(xs + (size_t)c0 * N);
        const float4* b1 = (const float4*)(xs + (size_t)c1 * N);

        float s00 = 0.f, s01 = 0.f, s10 = 0.f, s11 = 0.f;
        #pragma unroll
        for (int u = 0; u < N / 4 / 64; u++) {          // 12 iterations
            int idx = lane + u * 64;
            float4 va0 = a0[idx], va1 = a1[idx];
            float4 vb0 = b0[idx], vb1 = b1[idx];
            s00 += fabsf(va0.x - vb0.x) + fabsf(va0.y - vb0.y)
                 + fabsf(va0.z - vb0.z) + fabsf(va0.w - vb0.w);
            s01 += fabsf(va0.x - vb1.x) + fabsf(va0.y - vb1.y)
                 + fabsf(va0.z - vb1.z) + fabsf(va0.w - vb1.w);
            s10 += fabsf(va1.x - vb0.x) + fabsf(va1.y - vb0.y)
                 + fabsf(va1.z - vb0.z) + fabsf(va1.w - vb0.w);
            s11 += fabsf(va1.x - vb1.x) + fabsf(va1.y - vb1.y)
                 + fabsf(va1.z - vb1.z) + fabsf(va1.w - vb1.w);
        }
        #pragma unroll
        for (int o = 32; o > 0; o >>= 1) {
            s00 += __shfl_down(s00, o, 64);
            s01 += __shfl_down(s01, o, 64);
            s10 += __shfl_down(s10, o, 64);
            s11 += __shfl_down(s11, o, 64);
        }
        if (lane == 0) {
            bool diag = (ti == tj);
            float w00 = diag ? 1.0f : 2.0f;
            float w01 = 2.0f;
            float w10 = diag ? 0.0f : 2.0f;
            float w11 = diag ? 1.0f : 2.0f;
            float inv_n = 1.0f / N;
            float d00 = s00 * inv_n - (maxv - zcos[r0 * B + c0]);
            float d01 = s01 * inv_n - (maxv - zcos[r0 * B + c1]);
            float d10 = s10 * inv_n - (maxv - zcos[r1 * B + c0]);
            float d11 = s11 * inv_n - (maxv - zcos[r1 * B + c1]);
            acc += w00 * d00 * d00 + w01 * d01 * d01
                 + w10 * d10 * d10 + w11 * d11 * d11;
        }
    }
    if (lane == 0) partial[w] = acc;
    __syncthreads();
    if (tid == 0) {
        float blk = partial[0] + partial[1] + partial[2] + partial[3]
                  + partial[4] + partial[5] + partial[6] + partial[7];
        atomicAdd(out, blk * (1.0f / (B * B)));
    }
}

extern "C" void kernel_launch(void* const* d_in, const int* in_sizes, int n_in,
                              void* d_out, int out_size, void* d_ws, size_t ws_size,
                              hipStream_t stream) {
    const float* z = (const float*)d_in[0];   // [128,128]
    const float* x = (const float*)d_in[1];   // [128,3,32,32]
    float* out = (float*)d_out;               // [1]
    float* ws = (float*)d_ws;

    float* zcos = ws;                         // 16384 floats
    float* xs   = ws + 16384;                 // 393216 floats (sorted rows)
    float* maxv = ws + 16384 + 393216;        // 1 float

    prep_kernel<<<2 * B, NTHREADS, 0, stream>>>(x, z, xs, zcos, maxv, out);
    pair_kernel<<<2 * B, NTHREADS, 0, stream>>>(xs, zcos, maxv, out);
}